// Round 5
// baseline (407.667 us; speedup 1.0000x reference)
//
#include <hip/hip_runtime.h>

#define N_NODES 100000
#define N_EDGES 1600000
#define D 128
#define SCAN_CHUNK 1024
#define NB_SCAN ((N_NODES + SCAN_CHUNK - 1) / SCAN_CHUNK)  // 98

// binning config
#define BSHIFT 9
#define BUCK_NODES 512
#define NBUCK 196            // ceil(100000/512)
#define BCAP 24              // LDS staging records per bucket
#define SCAP 10240           // stage arena records per bucket (mean 8163, +23 sigma)
#define BIN_BLOCKS 200
#define EDGES_PER_BIN 8000   // 200*8000 = 1.6M

typedef __attribute__((ext_vector_type(8))) short bf16x8;
typedef __attribute__((ext_vector_type(4))) float f32x4;

__device__ __forceinline__ unsigned bf16rne(float f) {
  unsigned u = __float_as_uint(f);
  return (u + 0x7fffu + ((u >> 16) & 1u)) >> 16;
}

// ================= Tier-4 layout (int units) =================
// cnt   [0,100000)           histogram
// gcurA [100000,100196)      per-bucket stage cursors (zeroed with cnt)
// off   [100200,200201)      CSR offsets
// bsum  [200202,200300)
// fragW [200300,216684)      swizzled bf16 B-fragments
// srt   [216684,3416684)     int2 {src,w} exact CSR order
// xh    [3416684,9818732)    x bf16 (100032 rows)
// zh    [9818732,16220780)   z bf16 (100032 rows); stage arena ALIASED here
//                            (stage dead before gather writes zh)
#define T4_GCUR  100000
#define T4_OFF   100200
#define T4_BSUM  200202
#define T4_FRAGW 200300
#define T4_SRT   216684
#define T4_XH    3416684
#define T4_ZH    9818732
#define WS_T4_BYTES ((size_t)16220780 * 4)

// ---- round-3 fallback layout ----
#define WS_OFF   100000
#define WS_BSUM  200004
#define WS_SRT   200192
#define WS_XH    3400192
#define WS_T1_BYTES ((size_t)3400192 * 4)
#define WS_T2_BYTES ((size_t)(3400192 + 6400000) * 4)

// ================= T4 prep: hist + binA + x->bf16 + W swizzle =================
// blocks [0,200): bin 8000 edges each (hist atomic + LDS line-staged bucket append)
// blocks [200,6450): x -> bf16 (one uint4 group per thread)
// blocks [6450,6578): W -> bf16 MFMA-B fragment swizzle
__global__ __launch_bounds__(256) void prep_kernel(
    const int* __restrict__ ei, const float* __restrict__ ew,
    const float* __restrict__ x,
    const float* __restrict__ Wl, const float* __restrict__ Wa,
    int* __restrict__ cnt, int* __restrict__ gcurA,
    int2* __restrict__ stage, uint4* __restrict__ xh4,
    unsigned short* __restrict__ fragW) {
  __shared__ int cntL[NBUCK];
  __shared__ __align__(16) int2 bufS[NBUCK * BCAP];
  int bid = blockIdx.x;
  int tid = threadIdx.x;

  if (bid < BIN_BLOCKS) {
    if (tid < NBUCK) cntL[tid] = 0;
    __syncthreads();
    int e0 = bid * EDGES_PER_BIN;
    int e1 = e0 + EDGES_PER_BIN;
    for (int base_e = e0; base_e < e1; base_e += 256) {
      int e = base_e + tid;
      if (e < e1) {
        int dst = ei[e];
        atomicAdd(&cnt[dst], 1);
        int b = dst >> BSHIFT;
        int ldst = dst & (BUCK_NODES - 1);
        int2 rec = make_int2(ei[N_EDGES + e] | (ldst << 17), __float_as_int(ew[e]));
        int slot = atomicAdd(&cntL[b], 1);
        if (slot < BCAP) {
          bufS[b * BCAP + slot] = rec;
        } else {  // astronomically rare overflow: direct single-record append
          int p = atomicAdd(&gcurA[b], 1);
          stage[(size_t)b * SCAP + p] = rec;
        }
      }
      __syncthreads();
      if (tid < NBUCK) {
        int n = min(cntL[tid], BCAP);
        while (n >= 8) {
          int base = atomicAdd(&gcurA[tid], 8);
          int4* s4 = reinterpret_cast<int4*>(&bufS[tid * BCAP]);
          int4* d4 = reinterpret_cast<int4*>(stage + (size_t)tid * SCAP + base);
          d4[0] = s4[0]; d4[1] = s4[1]; d4[2] = s4[2]; d4[3] = s4[3];
          n -= 8;
          for (int i = 0; i < n; i++) bufS[tid * BCAP + i] = bufS[tid * BCAP + 8 + i];
        }
        cntL[tid] = n;
      }
      __syncthreads();
    }
    // drain leftovers (<8 per bucket)
    if (tid < NBUCK) {
      int n = cntL[tid];
      if (n > 0) {
        int base = atomicAdd(&gcurA[tid], n);
        for (int i = 0; i < n; i++)
          stage[(size_t)tid * SCAP + base + i] = bufS[tid * BCAP + i];
      }
    }
  } else if (bid < BIN_BLOCKS + 6250) {
    int g = (bid - BIN_BLOCKS) * 256 + tid;  // [0, 1.6M) uint4 groups
    const float4* xp = reinterpret_cast<const float4*>(x);
    float4 a = xp[(size_t)g * 2];
    float4 b = xp[(size_t)g * 2 + 1];
    uint4 o;
    o.x = bf16rne(a.x) | (bf16rne(a.y) << 16);
    o.y = bf16rne(a.z) | (bf16rne(a.w) << 16);
    o.z = bf16rne(b.x) | (bf16rne(b.y) << 16);
    o.w = bf16rne(b.z) | (bf16rne(b.w) << 16);
    xh4[g] = o;
  } else {
    int tau = (bid - BIN_BLOCKS - 6250) * 256 + tid;  // 0..32767
    int slot = tau >> 3, j = tau & 7;
    int lane = slot & 63, ft = slot >> 6;
    int t = ft & 7, s = ft >> 3;
    int kl = (s & 3) * 32 + (lane >> 4) * 8 + j;
    int n = t * 16 + (lane & 15);
    float v = (s < 4 ? Wl : Wa)[kl * 128 + n];
    fragW[slot * 8 + j] = (unsigned short)bf16rne(v);
  }
}

__global__ __launch_bounds__(256) void block_sum_kernel(const int* __restrict__ cnt,
                                                        int* __restrict__ bsum) {
  int base = blockIdx.x * SCAN_CHUNK;
  int s = 0;
#pragma unroll
  for (int k = 0; k < 4; k++) {
    int i = base + (int)threadIdx.x + k * 256;
    if (i < N_NODES) s += cnt[i];
  }
  __shared__ int red[4];
  for (int o = 32; o > 0; o >>= 1) s += __shfl_down(s, o, 64);
  if ((threadIdx.x & 63) == 0) red[threadIdx.x >> 6] = s;
  __syncthreads();
  if (threadIdx.x == 0) bsum[blockIdx.x] = red[0] + red[1] + red[2] + red[3];
}

__global__ __launch_bounds__(256) void scan2_kernel(int* __restrict__ cnt,
                                                    const int* __restrict__ bsum,
                                                    int* __restrict__ off) {
  __shared__ int sb[NB_SCAN + 1];
  __shared__ int sh[256];
  int t = threadIdx.x;
  if (t < NB_SCAN) sb[t] = bsum[t];
  __syncthreads();
  if (t == 0) {
    int run = 0;
    for (int i = 0; i < NB_SCAN; i++) { int c = sb[i]; sb[i] = run; run += c; }
    sb[NB_SCAN] = run;
  }
  __syncthreads();
  int i0 = blockIdx.x * SCAN_CHUNK + t * 4;
  int c[4];
#pragma unroll
  for (int k = 0; k < 4; k++) c[k] = (i0 + k < N_NODES) ? cnt[i0 + k] : 0;
  int ls = c[0] + c[1] + c[2] + c[3];
  sh[t] = ls;
  __syncthreads();
  for (int o = 1; o < 256; o <<= 1) {
    int add = (t >= o) ? sh[t - o] : 0;
    __syncthreads();
    sh[t] += add;
    __syncthreads();
  }
  int run = sb[blockIdx.x] + sh[t] - ls;
#pragma unroll
  for (int k = 0; k < 4; k++) {
    if (i0 + k < N_NODES) { off[i0 + k] = run; run += c[k]; }
  }
  if (blockIdx.x == 0 && t == 0) off[N_NODES] = sb[NB_SCAN];
}

// binB: one block per bucket; scatter stage records to exact CSR slots.
// Writes stay inside a ~131 KB region owned by this block -> lines merge in L2.
__global__ __launch_bounds__(256) void binB_kernel(const int2* __restrict__ stage,
                                                   const int* __restrict__ gcurA,
                                                   const int* __restrict__ off,
                                                   int2* __restrict__ srt) {
  __shared__ int curL[BUCK_NODES];
  int b = blockIdx.x;
  int tid = threadIdx.x;
  int nb = b << BSHIFT;
  int nn = min(BUCK_NODES, N_NODES - nb);
  for (int i = tid; i < nn; i += 256) curL[i] = off[nb + i];
  __syncthreads();
  int m = gcurA[b];
  const int2* sp = stage + (size_t)b * SCAP;
  for (int r = tid; r < m; r += 256) {
    int2 rec = sp[r];
    int ldst = ((unsigned)rec.x) >> 17;
    int src = rec.x & 0x1FFFF;
    int p = atomicAdd(&curL[ldst], 1);
    srt[p] = make_int2(src, rec.y);
  }
}

// gather: half-wave per node, bf16 rows, 4-edge software pipeline
__global__ __launch_bounds__(256) void gather_zh_kernel(const unsigned* __restrict__ xh,
                                                        const int* __restrict__ off,
                                                        const int2* __restrict__ srt,
                                                        unsigned* __restrict__ zh) {
  int gid = blockIdx.x * 256 + threadIdx.x;
  int n = gid >> 5;
  int lane = gid & 31;
  int beg = off[n], end = off[n + 1];
  float4 acc = make_float4(0.f, 0.f, 0.f, 0.f);
  int e = beg;
  for (; e + 3 < end; e += 4) {
    int2 r0 = srt[e];
    int2 r1 = srt[e + 1];
    int2 r2 = srt[e + 2];
    int2 r3 = srt[e + 3];
    uint2 p0 = *reinterpret_cast<const uint2*>(xh + (size_t)r0.x * 64 + lane * 2);
    uint2 p1 = *reinterpret_cast<const uint2*>(xh + (size_t)r1.x * 64 + lane * 2);
    uint2 p2 = *reinterpret_cast<const uint2*>(xh + (size_t)r2.x * 64 + lane * 2);
    uint2 p3 = *reinterpret_cast<const uint2*>(xh + (size_t)r3.x * 64 + lane * 2);
    float w0 = __int_as_float(r0.y), w1 = __int_as_float(r1.y);
    float w2 = __int_as_float(r2.y), w3 = __int_as_float(r3.y);
    acc.x = fmaf(w0, __uint_as_float(p0.x << 16), acc.x);
    acc.y = fmaf(w0, __uint_as_float(p0.x & 0xffff0000u), acc.y);
    acc.z = fmaf(w0, __uint_as_float(p0.y << 16), acc.z);
    acc.w = fmaf(w0, __uint_as_float(p0.y & 0xffff0000u), acc.w);
    acc.x = fmaf(w1, __uint_as_float(p1.x << 16), acc.x);
    acc.y = fmaf(w1, __uint_as_float(p1.x & 0xffff0000u), acc.y);
    acc.z = fmaf(w1, __uint_as_float(p1.y << 16), acc.z);
    acc.w = fmaf(w1, __uint_as_float(p1.y & 0xffff0000u), acc.w);
    acc.x = fmaf(w2, __uint_as_float(p2.x << 16), acc.x);
    acc.y = fmaf(w2, __uint_as_float(p2.x & 0xffff0000u), acc.y);
    acc.z = fmaf(w2, __uint_as_float(p2.y << 16), acc.z);
    acc.w = fmaf(w2, __uint_as_float(p2.y & 0xffff0000u), acc.w);
    acc.x = fmaf(w3, __uint_as_float(p3.x << 16), acc.x);
    acc.y = fmaf(w3, __uint_as_float(p3.x & 0xffff0000u), acc.y);
    acc.z = fmaf(w3, __uint_as_float(p3.y << 16), acc.z);
    acc.w = fmaf(w3, __uint_as_float(p3.y & 0xffff0000u), acc.w);
  }
  for (; e < end; e++) {
    int2 r0 = srt[e];
    uint2 p0 = *reinterpret_cast<const uint2*>(xh + (size_t)r0.x * 64 + lane * 2);
    float w0 = __int_as_float(r0.y);
    acc.x = fmaf(w0, __uint_as_float(p0.x << 16), acc.x);
    acc.y = fmaf(w0, __uint_as_float(p0.x & 0xffff0000u), acc.y);
    acc.z = fmaf(w0, __uint_as_float(p0.y << 16), acc.z);
    acc.w = fmaf(w0, __uint_as_float(p0.y & 0xffff0000u), acc.w);
  }
  uint2 o;
  o.x = bf16rne(acc.x) | (bf16rne(acc.y) << 16);
  o.y = bf16rne(acc.z) | (bf16rne(acc.w) << 16);
  *reinterpret_cast<uint2*>(zh + (size_t)n * 64 + lane * 2) = o;
}

// MFMA GEMM: out = [xh|zh] @ [Wl;Wa] + bl + deg*ba (deg from off)
__global__ __launch_bounds__(256) void mfma_gemm_kernel(
    const short* __restrict__ xh, const short* __restrict__ zh,
    const short* __restrict__ fragW, const int* __restrict__ off,
    const float* __restrict__ bl, const float* __restrict__ ba,
    float* __restrict__ out) {
  int tid = threadIdx.x;
  int wave = tid >> 6, lane = tid & 63;
  int m = lane & 15, q = lane >> 4;
  int R = blockIdx.x * 64 + wave * 16;
  const short* xrow = xh + (size_t)(R + m) * D + q * 8;
  const short* zrow = zh + (size_t)(R + m) * D + q * 8;
  const short* fw = fragW + (size_t)lane * 8;

  f32x4 acc[8];
#pragma unroll
  for (int t = 0; t < 8; t++) acc[t] = (f32x4){0.f, 0.f, 0.f, 0.f};

#pragma unroll
  for (int s = 0; s < 8; s++) {
    bf16x8 a = *reinterpret_cast<const bf16x8*>(s < 4 ? xrow + s * 32
                                                      : zrow + (s - 4) * 32);
#pragma unroll
    for (int t = 0; t < 8; t++) {
      bf16x8 b = *reinterpret_cast<const bf16x8*>(fw + (size_t)((s * 8 + t) * 64) * 8);
      acc[t] = __builtin_amdgcn_mfma_f32_16x16x32_bf16(a, b, acc[t], 0, 0, 0);
    }
  }

  float blv[8], bav[8];
#pragma unroll
  for (int t = 0; t < 8; t++) {
    blv[t] = bl[t * 16 + m];
    bav[t] = ba[t * 16 + m];
  }
#pragma unroll
  for (int r = 0; r < 4; r++) {
    int row = R + q * 4 + r;
    if (row < N_NODES) {
      float dg = (float)(off[row + 1] - off[row]);
#pragma unroll
      for (int t = 0; t < 8; t++)
        out[(size_t)row * D + t * 16 + m] = acc[t][r] + blv[t] + dg * bav[t];
    }
  }
}

// ================= fallback kernels (tiers 0-2) =================

__global__ __launch_bounds__(256) void hist_kernel(const int* __restrict__ ei,
                                                   int* __restrict__ cnt) {
  int e = blockIdx.x * 256 + threadIdx.x;
  if (e < N_EDGES) atomicAdd(&cnt[ei[e]], 1);
}

__global__ __launch_bounds__(128) void scan_bsum_kernel(int* __restrict__ bsum,
                                                        int* __restrict__ off) {
  __shared__ int sh[128];
  int t = threadIdx.x;
  int v = (t < NB_SCAN) ? bsum[t] : 0;
  sh[t] = v;
  __syncthreads();
  for (int o = 1; o < 128; o <<= 1) {
    int add = (t >= o) ? sh[t - o] : 0;
    __syncthreads();
    sh[t] += add;
    __syncthreads();
  }
  if (t < NB_SCAN) bsum[t] = sh[t] - v;
  if (t == 0) off[N_NODES] = sh[127];
}

__global__ __launch_bounds__(256) void scan_offsets_kernel(const int* __restrict__ cnt,
                                                           const int* __restrict__ bsum,
                                                           int* __restrict__ off) {
  __shared__ int sh[256];
  int t = threadIdx.x;
  int i0 = blockIdx.x * SCAN_CHUNK + t * 4;
  int c[4];
#pragma unroll
  for (int k = 0; k < 4; k++) c[k] = (i0 + k < N_NODES) ? cnt[i0 + k] : 0;
  int ls = c[0] + c[1] + c[2] + c[3];
  sh[t] = ls;
  __syncthreads();
  for (int o = 1; o < 256; o <<= 1) {
    int add = (t >= o) ? sh[t - o] : 0;
    __syncthreads();
    sh[t] += add;
    __syncthreads();
  }
  int run = bsum[blockIdx.x] + sh[t] - ls;
#pragma unroll
  for (int k = 0; k < 4; k++) {
    if (i0 + k < N_NODES) off[i0 + k] = run;
    run += c[k];
  }
}

__global__ __launch_bounds__(256) void fill_kernel(const int* __restrict__ ei,
                                                   const float* __restrict__ ew,
                                                   const int* __restrict__ off,
                                                   int* __restrict__ cur,
                                                   int2* __restrict__ srt) {
  int e = blockIdx.x * 256 + threadIdx.x;
  if (e >= N_EDGES) return;
  int dst = ei[e];
  int p = off[dst] + atomicAdd(&cur[dst], 1);
  srt[p] = make_int2(ei[N_EDGES + e], __float_as_int(ew[e]));
}

__global__ __launch_bounds__(256) void convert_kernel(const float* __restrict__ x,
                                                      uint4* __restrict__ xh) {
  int i = blockIdx.x * 256 + threadIdx.x;
  const float4* xp = reinterpret_cast<const float4*>(x);
  float4 a = xp[(size_t)i * 2];
  float4 b = xp[(size_t)i * 2 + 1];
  uint4 o;
  o.x = bf16rne(a.x) | (bf16rne(a.y) << 16);
  o.y = bf16rne(a.z) | (bf16rne(a.w) << 16);
  o.z = bf16rne(b.x) | (bf16rne(b.y) << 16);
  o.w = bf16rne(b.z) | (bf16rne(b.w) << 16);
  xh[i] = o;
}

__global__ __launch_bounds__(256) void gather_bf16_kernel(const unsigned* __restrict__ xh,
                                                          const int* __restrict__ off,
                                                          const int2* __restrict__ srt,
                                                          float* __restrict__ z,
                                                          float* __restrict__ degf) {
  int gid = blockIdx.x * 256 + threadIdx.x;
  int n = gid >> 5;
  int lane = gid & 31;
  if (n >= N_NODES) return;
  int beg = off[n], end = off[n + 1];
  float4 acc = make_float4(0.f, 0.f, 0.f, 0.f);
  int e = beg;
  for (; e + 1 < end; e += 2) {
    int2 r0 = srt[e];
    int2 r1 = srt[e + 1];
    uint2 p0 = *reinterpret_cast<const uint2*>(xh + (size_t)r0.x * 64 + lane * 2);
    uint2 p1 = *reinterpret_cast<const uint2*>(xh + (size_t)r1.x * 64 + lane * 2);
    float w0 = __int_as_float(r0.y);
    float w1 = __int_as_float(r1.y);
    acc.x = fmaf(w0, __uint_as_float(p0.x << 16), acc.x);
    acc.y = fmaf(w0, __uint_as_float(p0.x & 0xffff0000u), acc.y);
    acc.z = fmaf(w0, __uint_as_float(p0.y << 16), acc.z);
    acc.w = fmaf(w0, __uint_as_float(p0.y & 0xffff0000u), acc.w);
    acc.x = fmaf(w1, __uint_as_float(p1.x << 16), acc.x);
    acc.y = fmaf(w1, __uint_as_float(p1.x & 0xffff0000u), acc.y);
    acc.z = fmaf(w1, __uint_as_float(p1.y << 16), acc.z);
    acc.w = fmaf(w1, __uint_as_float(p1.y & 0xffff0000u), acc.w);
  }
  if (e < end) {
    int2 r0 = srt[e];
    uint2 p0 = *reinterpret_cast<const uint2*>(xh + (size_t)r0.x * 64 + lane * 2);
    float w0 = __int_as_float(r0.y);
    acc.x = fmaf(w0, __uint_as_float(p0.x << 16), acc.x);
    acc.y = fmaf(w0, __uint_as_float(p0.x & 0xffff0000u), acc.y);
    acc.z = fmaf(w0, __uint_as_float(p0.y << 16), acc.z);
    acc.w = fmaf(w0, __uint_as_float(p0.y & 0xffff0000u), acc.w);
  }
  *reinterpret_cast<float4*>(z + (size_t)n * D + (lane << 2)) = acc;
  if (lane == 0) degf[n] = (float)(end - beg);
}

__global__ __launch_bounds__(256) void gather_f32_kernel(const float* __restrict__ x,
                                                         const int* __restrict__ off,
                                                         const int2* __restrict__ srt,
                                                         float* __restrict__ z,
                                                         float* __restrict__ degf) {
  int gid = blockIdx.x * 256 + threadIdx.x;
  int n = gid >> 5;
  int lane = gid & 31;
  if (n >= N_NODES) return;
  int beg = off[n], end = off[n + 1];
  float4 acc = make_float4(0.f, 0.f, 0.f, 0.f);
  for (int e = beg; e < end; e++) {
    int2 r0 = srt[e];
    float4 x0 = *reinterpret_cast<const float4*>(x + (size_t)r0.x * D + (lane << 2));
    float w0 = __int_as_float(r0.y);
    acc.x = fmaf(w0, x0.x, acc.x); acc.y = fmaf(w0, x0.y, acc.y);
    acc.z = fmaf(w0, x0.z, acc.z); acc.w = fmaf(w0, x0.w, acc.w);
  }
  *reinterpret_cast<float4*>(z + (size_t)n * D + (lane << 2)) = acc;
  if (lane == 0) degf[n] = (float)(end - beg);
}

__global__ __launch_bounds__(256) void scatter_kernel(const float* __restrict__ x,
                                                      const int* __restrict__ ei,
                                                      const float* __restrict__ ew,
                                                      float* __restrict__ z,
                                                      float* __restrict__ deg) {
  long long g = (long long)blockIdx.x * 256 + threadIdx.x;
  int e = (int)(g >> 5);
  int lane = (int)(g & 31);
  if (e >= N_EDGES) return;
  int dst = ei[e];
  int src = ei[N_EDGES + e];
  float w = ew[e];
  float4 xv = *reinterpret_cast<const float4*>(x + (size_t)src * D + (lane << 2));
  float* o = z + (size_t)dst * D + (lane << 2);
  atomicAdd(o + 0, w * xv.x);
  atomicAdd(o + 1, w * xv.y);
  atomicAdd(o + 2, w * xv.z);
  atomicAdd(o + 3, w * xv.w);
  if (lane == 0) atomicAdd(deg + dst, 1.0f);
}

__global__ __launch_bounds__(256) void fused_gemm_kernel(const float* __restrict__ x,
                                                         const float* __restrict__ Wl,
                                                         const float* __restrict__ bl,
                                                         const float* __restrict__ Wa,
                                                         const float* __restrict__ ba,
                                                         const float* __restrict__ deg,
                                                         float* __restrict__ out) {
  __shared__ float xs[32 * 16];
  __shared__ float zs[32 * 16];
  __shared__ float wls[16 * 128];
  __shared__ float was[16 * 128];
  const int tid = threadIdx.x;
  const int row0 = blockIdx.x * 32;
  const int c4 = tid & 31;
  const int r0 = tid >> 5;
  float4 acc[4];
#pragma unroll
  for (int i = 0; i < 4; i++) acc[i] = make_float4(0.f, 0.f, 0.f, 0.f);

  for (int k0 = 0; k0 < D; k0 += 16) {
    {
      int t = tid & 127;
      int r = t >> 2;
      int kc = (t & 3) << 2;
      const float* sp = (tid < 128) ? x : out;
      float* dp = (tid < 128) ? xs : zs;
      *reinterpret_cast<float4*>(dp + r * 16 + kc) =
          *reinterpret_cast<const float4*>(sp + (size_t)(row0 + r) * D + k0 + kc);
    }
#pragma unroll
    for (int i = 0; i < 2; i++) {
      int f = tid + i * 256;
      int kk = f >> 5;
      int cc = (f & 31) << 2;
      *reinterpret_cast<float4*>(wls + kk * 128 + cc) =
          *reinterpret_cast<const float4*>(Wl + (size_t)(k0 + kk) * D + cc);
      *reinterpret_cast<float4*>(was + kk * 128 + cc) =
          *reinterpret_cast<const float4*>(Wa + (size_t)(k0 + kk) * D + cc);
    }
    __syncthreads();
#pragma unroll
    for (int kk = 0; kk < 16; kk++) {
      float4 wl = *reinterpret_cast<const float4*>(wls + kk * 128 + (c4 << 2));
      float4 wa = *reinterpret_cast<const float4*>(was + kk * 128 + (c4 << 2));
#pragma unroll
      for (int rr = 0; rr < 4; rr++) {
        int r2 = r0 + rr * 8;
        float xv = xs[r2 * 16 + kk];
        float zv = zs[r2 * 16 + kk];
        acc[rr].x = fmaf(xv, wl.x, fmaf(zv, wa.x, acc[rr].x));
        acc[rr].y = fmaf(xv, wl.y, fmaf(zv, wa.y, acc[rr].y));
        acc[rr].z = fmaf(xv, wl.z, fmaf(zv, wa.z, acc[rr].z));
        acc[rr].w = fmaf(xv, wl.w, fmaf(zv, wa.w, acc[rr].w));
      }
    }
    __syncthreads();
  }

  float4 blv = *reinterpret_cast<const float4*>(bl + (c4 << 2));
  float4 bav = *reinterpret_cast<const float4*>(ba + (c4 << 2));
#pragma unroll
  for (int rr = 0; rr < 4; rr++) {
    int r = row0 + r0 + rr * 8;
    float d = deg[r];
    float4 o;
    o.x = acc[rr].x + blv.x + d * bav.x;
    o.y = acc[rr].y + blv.y + d * bav.y;
    o.z = acc[rr].z + blv.z + d * bav.z;
    o.w = acc[rr].w + blv.w + d * bav.w;
    *reinterpret_cast<float4*>(out + (size_t)r * D + (c4 << 2)) = o;
  }
}

extern "C" void kernel_launch(void* const* d_in, const int* in_sizes, int n_in,
                              void* d_out, int out_size, void* d_ws, size_t ws_size,
                              hipStream_t stream) {
  const float* x  = (const float*)d_in[0];
  const int*   ei = (const int*)d_in[1];
  const float* ew = (const float*)d_in[2];
  const float* Wl = (const float*)d_in[3];
  const float* bl = (const float*)d_in[4];
  const float* Wa = (const float*)d_in[5];
  const float* ba = (const float*)d_in[6];
  float* out = (float*)d_out;

  if (ws_size >= WS_T4_BYTES) {
    int* cnt = (int*)d_ws;
    int* gcurA = cnt + T4_GCUR;
    int* off = cnt + T4_OFF;
    int* bsum = cnt + T4_BSUM;
    unsigned short* fragW = (unsigned short*)(cnt + T4_FRAGW);
    int2* srt = (int2*)(cnt + T4_SRT);
    unsigned* xh = (unsigned*)(cnt + T4_XH);
    unsigned* zh = (unsigned*)(cnt + T4_ZH);
    int2* stage = (int2*)(cnt + T4_ZH);  // time-aliased with zh

    hipMemsetAsync(cnt, 0, (size_t)(100196) * sizeof(int), stream);  // cnt + gcurA
    prep_kernel<<<BIN_BLOCKS + 6250 + 128, 256, 0, stream>>>(
        ei, ew, x, Wl, Wa, cnt, gcurA, stage, (uint4*)xh, fragW);
    block_sum_kernel<<<NB_SCAN, 256, 0, stream>>>(cnt, bsum);
    scan2_kernel<<<NB_SCAN, 256, 0, stream>>>(cnt, bsum, off);
    binB_kernel<<<NBUCK, 256, 0, stream>>>(stage, gcurA, off, srt);
    gather_zh_kernel<<<N_NODES * 32 / 256, 256, 0, stream>>>(xh, off, srt, zh);
    mfma_gemm_kernel<<<1563, 256, 0, stream>>>((const short*)xh, (const short*)zh,
                                               (const short*)fragW, off, bl, ba, out);
  } else if (ws_size >= WS_T1_BYTES) {
    int*  cnt  = (int*)d_ws;
    int*  off  = cnt + WS_OFF;
    int*  bsum = cnt + WS_BSUM;
    int2* srt  = (int2*)(cnt + WS_SRT);
    float* degf = (float*)cnt;

    hipMemsetAsync(cnt, 0, (size_t)N_NODES * sizeof(int), stream);
    hist_kernel<<<(N_EDGES + 255) / 256, 256, 0, stream>>>(ei, cnt);
    block_sum_kernel<<<NB_SCAN, 256, 0, stream>>>(cnt, bsum);
    scan_bsum_kernel<<<1, 128, 0, stream>>>(bsum, off);
    scan_offsets_kernel<<<NB_SCAN, 256, 0, stream>>>(cnt, bsum, off);
    hipMemsetAsync(cnt, 0, (size_t)N_NODES * sizeof(int), stream);
    fill_kernel<<<(N_EDGES + 255) / 256, 256, 0, stream>>>(ei, ew, off, cnt, srt);

    if (ws_size >= WS_T2_BYTES) {
      unsigned* xh = (unsigned*)(cnt + WS_XH);
      convert_kernel<<<(N_NODES * D / 8) / 256, 256, 0, stream>>>(x, (uint4*)xh);
      gather_bf16_kernel<<<(N_NODES * 32 + 255) / 256, 256, 0, stream>>>(xh, off, srt, out, degf);
    } else {
      gather_f32_kernel<<<(N_NODES * 32 + 255) / 256, 256, 0, stream>>>(x, off, srt, out, degf);
    }
    fused_gemm_kernel<<<N_NODES / 32, 256, 0, stream>>>(x, Wl, bl, Wa, ba, degf, out);
  } else {
    float* deg = (float*)d_ws;
    hipMemsetAsync(out, 0, (size_t)N_NODES * D * sizeof(float), stream);
    hipMemsetAsync(deg, 0, (size_t)N_NODES * sizeof(float), stream);
    scatter_kernel<<<(N_EDGES * 32) / 256, 256, 0, stream>>>(x, ei, ew, out, deg);
    fused_gemm_kernel<<<N_NODES / 32, 256, 0, stream>>>(x, Wl, bl, Wa, ba, deg, out);
  }
}

// Round 6
// 284.452 us; speedup vs baseline: 1.4332x; 1.4332x over previous
//
#include <hip/hip_runtime.h>

#define N_NODES 100000
#define N_EDGES 1600000
#define D 128
#define SCAN_CHUNK 1024
#define NB_SCAN ((N_NODES + SCAN_CHUNK - 1) / SCAN_CHUNK)  // 98

// bucket/partition config
#define BSHIFT 9
#define BUCK_NODES 512
#define NBUCK 196              // ceil(100000/512)
#define SCAP 10240             // stage arena records per bucket (mean 8163)
#define PART_CHUNK 4096
#define PART_BLOCKS ((N_EDGES + PART_CHUNK - 1) / PART_CHUNK)  // 391
#define CONV_BLOCKS 6250
#define W_BLOCKS 128

typedef __attribute__((ext_vector_type(8))) short bf16x8;
typedef __attribute__((ext_vector_type(4))) float f32x4;

__device__ __forceinline__ unsigned bf16rne(float f) {
  unsigned u = __float_as_uint(f);
  return (u + 0x7fffu + ((u >> 16) & 1u)) >> 16;
}

// ================= Tier-5 layout (int units) =================
// pcur  [0,196)              per-bucket stage cursors
// off   [200,100301)         CSR offsets (100001)
// fragW [100304,116688)      swizzled bf16 B-fragments (32768 bf16)
// srt   [116688,3316688)     int2 {src,w} exact CSR order
// xh    [3316688,9718736)    x bf16 (100032 rows)
// zh    [9718736,16120784)   z bf16 (100032 rows); stage arena ALIASED here
#define T5_OFF    200
#define T5_FRAGW  100304
#define T5_SRT    116688
#define T5_XH     3316688
#define T5_ZH     9718736
#define WS_T5_BYTES ((size_t)16120784 * 4)

// ---- fallback layouts (rounds 1-3) ----
#define WS_OFF   100000
#define WS_BSUM  200004
#define WS_SRT   200192
#define WS_XH    3400192
#define WS_T1_BYTES ((size_t)3400192 * 4)
#define WS_T2_BYTES ((size_t)(3400192 + 6400000) * 4)

// ============ T5 part: edge multi-split + x->bf16 + W swizzle ============
// blocks [0,391): partition 4096 edges each into 196 bucket arenas.
//   LDS hist -> one global reservation per (block,bucket) -> thread-parallel
//   stores into block-owned runs (lines complete inside one L2).
// blocks [391,6641): x -> bf16.   blocks [6641,6769): W -> MFMA-B fragments.
__global__ __launch_bounds__(256) void part_kernel(
    const int* __restrict__ ei, const float* __restrict__ ew,
    const float* __restrict__ x,
    const float* __restrict__ Wl, const float* __restrict__ Wa,
    int* __restrict__ pcur, int2* __restrict__ stage,
    uint4* __restrict__ xh4, unsigned short* __restrict__ fragW) {
  __shared__ int cntL[NBUCK];
  __shared__ int gbaseL[NBUCK];
  __shared__ int curL[NBUCK];
  int bid = blockIdx.x, tid = threadIdx.x;

  if (bid < PART_BLOCKS) {
    if (tid < NBUCK) cntL[tid] = 0;
    __syncthreads();
    int e0 = bid * PART_CHUNK;
#pragma unroll
    for (int k = 0; k < PART_CHUNK / 256; k++) {
      int e = e0 + k * 256 + tid;
      if (e < N_EDGES) atomicAdd(&cntL[ei[e] >> BSHIFT], 1);
    }
    __syncthreads();
    if (tid < NBUCK) {
      gbaseL[tid] = atomicAdd(&pcur[tid], cntL[tid]);
      curL[tid] = 0;
    }
    __syncthreads();
#pragma unroll
    for (int k = 0; k < PART_CHUNK / 256; k++) {
      int e = e0 + k * 256 + tid;
      if (e < N_EDGES) {
        int d = ei[e];
        int b = d >> BSHIFT;
        int s = atomicAdd(&curL[b], 1);
        stage[(size_t)b * SCAP + gbaseL[b] + s] = make_int2(
            ei[N_EDGES + e] | ((d & (BUCK_NODES - 1)) << 17), __float_as_int(ew[e]));
      }
    }
  } else if (bid < PART_BLOCKS + CONV_BLOCKS) {
    int g = (bid - PART_BLOCKS) * 256 + tid;  // [0, 1.6M) uint4 groups
    const float4* xp = reinterpret_cast<const float4*>(x);
    float4 a = xp[(size_t)g * 2];
    float4 b = xp[(size_t)g * 2 + 1];
    uint4 o;
    o.x = bf16rne(a.x) | (bf16rne(a.y) << 16);
    o.y = bf16rne(a.z) | (bf16rne(a.w) << 16);
    o.z = bf16rne(b.x) | (bf16rne(b.y) << 16);
    o.w = bf16rne(b.z) | (bf16rne(b.w) << 16);
    xh4[g] = o;
  } else {
    int tau = (bid - PART_BLOCKS - CONV_BLOCKS) * 256 + tid;  // 0..32767
    int slot = tau >> 3, j = tau & 7;
    int lane = slot & 63, ft = slot >> 6;
    int t = ft & 7, s = ft >> 3;
    int kl = (s & 3) * 32 + (lane >> 4) * 8 + j;
    int n = t * 16 + (lane & 15);
    float v = (s < 4 ? Wl : Wa)[kl * 128 + n];
    fragW[slot * 8 + j] = (unsigned short)bf16rne(v);
  }
}

// ============ T5 binB2: per-bucket LDS hist + scan -> off[] + exact scatter ====
__global__ __launch_bounds__(256) void binB2_kernel(const int* __restrict__ pcur,
                                                    const int2* __restrict__ stage,
                                                    int* __restrict__ off,
                                                    int2* __restrict__ srt) {
  __shared__ int pc[NBUCK];
  __shared__ int sa[BUCK_NODES];
  __shared__ int sb[BUCK_NODES];
  __shared__ int curL[BUCK_NODES];
  __shared__ int baseS, mS;
  int b = blockIdx.x, tid = threadIdx.x;
  if (tid < NBUCK) pc[tid] = pcur[tid];
  for (int i = tid; i < BUCK_NODES; i += 256) sa[i] = 0;
  __syncthreads();
  if (tid == 0) {
    int s = 0;
    for (int i = 0; i < b; i++) s += pc[i];
    baseS = s;
    mS = pc[b];
  }
  __syncthreads();
  int base = baseS, m = mS;
  const int2* sp = stage + (size_t)b * SCAP;
  for (int r = tid; r < m; r += 256)
    atomicAdd(&sa[((unsigned)sp[r].x) >> 17], 1);
  __syncthreads();
  // Hillis-Steele inclusive scan over 512 (256 threads, 2 elems each, dbl-buf)
  int* srcb = sa;
  int* dstb = sb;
  for (int o = 1; o < BUCK_NODES; o <<= 1) {
    for (int p = tid; p < BUCK_NODES; p += 256)
      dstb[p] = srcb[p] + (p >= o ? srcb[p - o] : 0);
    __syncthreads();
    int* t = srcb; srcb = dstb; dstb = t;
  }
  int nb = b << BSHIFT;
  int nn = min(BUCK_NODES, N_NODES - nb);
  for (int i = tid; i < BUCK_NODES; i += 256) {
    int ex = i ? srcb[i - 1] : 0;
    curL[i] = ex;
    if (i < nn) off[nb + i] = base + ex;
  }
  if (tid == 0 && b == NBUCK - 1) off[N_NODES] = base + srcb[nn - 1];
  __syncthreads();
  for (int r = tid; r < m; r += 256) {
    int2 rec = sp[r];
    int ldst = ((unsigned)rec.x) >> 17;
    int s = atomicAdd(&curL[ldst], 1);
    srt[base + s] = make_int2(rec.x & 0x1FFFF, rec.y);
  }
}

// ============ gather: half-wave per node, bf16 rows, 4-edge pipeline ============
__global__ __launch_bounds__(256) void gather_zh_kernel(const unsigned* __restrict__ xh,
                                                        const int* __restrict__ off,
                                                        const int2* __restrict__ srt,
                                                        unsigned* __restrict__ zh) {
  int gid = blockIdx.x * 256 + threadIdx.x;
  int n = gid >> 5;
  int lane = gid & 31;
  int beg = off[n], end = off[n + 1];
  float4 acc = make_float4(0.f, 0.f, 0.f, 0.f);
  int e = beg;
  for (; e + 3 < end; e += 4) {
    int2 r0 = srt[e];
    int2 r1 = srt[e + 1];
    int2 r2 = srt[e + 2];
    int2 r3 = srt[e + 3];
    uint2 p0 = *reinterpret_cast<const uint2*>(xh + (size_t)r0.x * 64 + lane * 2);
    uint2 p1 = *reinterpret_cast<const uint2*>(xh + (size_t)r1.x * 64 + lane * 2);
    uint2 p2 = *reinterpret_cast<const uint2*>(xh + (size_t)r2.x * 64 + lane * 2);
    uint2 p3 = *reinterpret_cast<const uint2*>(xh + (size_t)r3.x * 64 + lane * 2);
    float w0 = __int_as_float(r0.y), w1 = __int_as_float(r1.y);
    float w2 = __int_as_float(r2.y), w3 = __int_as_float(r3.y);
    acc.x = fmaf(w0, __uint_as_float(p0.x << 16), acc.x);
    acc.y = fmaf(w0, __uint_as_float(p0.x & 0xffff0000u), acc.y);
    acc.z = fmaf(w0, __uint_as_float(p0.y << 16), acc.z);
    acc.w = fmaf(w0, __uint_as_float(p0.y & 0xffff0000u), acc.w);
    acc.x = fmaf(w1, __uint_as_float(p1.x << 16), acc.x);
    acc.y = fmaf(w1, __uint_as_float(p1.x & 0xffff0000u), acc.y);
    acc.z = fmaf(w1, __uint_as_float(p1.y << 16), acc.z);
    acc.w = fmaf(w1, __uint_as_float(p1.y & 0xffff0000u), acc.w);
    acc.x = fmaf(w2, __uint_as_float(p2.x << 16), acc.x);
    acc.y = fmaf(w2, __uint_as_float(p2.x & 0xffff0000u), acc.y);
    acc.z = fmaf(w2, __uint_as_float(p2.y << 16), acc.z);
    acc.w = fmaf(w2, __uint_as_float(p2.y & 0xffff0000u), acc.w);
    acc.x = fmaf(w3, __uint_as_float(p3.x << 16), acc.x);
    acc.y = fmaf(w3, __uint_as_float(p3.x & 0xffff0000u), acc.y);
    acc.z = fmaf(w3, __uint_as_float(p3.y << 16), acc.z);
    acc.w = fmaf(w3, __uint_as_float(p3.y & 0xffff0000u), acc.w);
  }
  for (; e < end; e++) {
    int2 r0 = srt[e];
    uint2 p0 = *reinterpret_cast<const uint2*>(xh + (size_t)r0.x * 64 + lane * 2);
    float w0 = __int_as_float(r0.y);
    acc.x = fmaf(w0, __uint_as_float(p0.x << 16), acc.x);
    acc.y = fmaf(w0, __uint_as_float(p0.x & 0xffff0000u), acc.y);
    acc.z = fmaf(w0, __uint_as_float(p0.y << 16), acc.z);
    acc.w = fmaf(w0, __uint_as_float(p0.y & 0xffff0000u), acc.w);
  }
  uint2 o;
  o.x = bf16rne(acc.x) | (bf16rne(acc.y) << 16);
  o.y = bf16rne(acc.z) | (bf16rne(acc.w) << 16);
  *reinterpret_cast<uint2*>(zh + (size_t)n * 64 + lane * 2) = o;
}

// ============ MFMA GEMM: out = [xh|zh] @ [Wl;Wa] + bl + deg*ba ============
__global__ __launch_bounds__(256) void mfma_gemm_kernel(
    const short* __restrict__ xh, const short* __restrict__ zh,
    const short* __restrict__ fragW, const int* __restrict__ off,
    const float* __restrict__ bl, const float* __restrict__ ba,
    float* __restrict__ out) {
  int tid = threadIdx.x;
  int wave = tid >> 6, lane = tid & 63;
  int m = lane & 15, q = lane >> 4;
  int R = blockIdx.x * 64 + wave * 16;
  const short* xrow = xh + (size_t)(R + m) * D + q * 8;
  const short* zrow = zh + (size_t)(R + m) * D + q * 8;
  const short* fw = fragW + (size_t)lane * 8;

  f32x4 acc[8];
#pragma unroll
  for (int t = 0; t < 8; t++) acc[t] = (f32x4){0.f, 0.f, 0.f, 0.f};

#pragma unroll
  for (int s = 0; s < 8; s++) {
    bf16x8 a = *reinterpret_cast<const bf16x8*>(s < 4 ? xrow + s * 32
                                                      : zrow + (s - 4) * 32);
#pragma unroll
    for (int t = 0; t < 8; t++) {
      bf16x8 b = *reinterpret_cast<const bf16x8*>(fw + (size_t)((s * 8 + t) * 64) * 8);
      acc[t] = __builtin_amdgcn_mfma_f32_16x16x32_bf16(a, b, acc[t], 0, 0, 0);
    }
  }

  float blv[8], bav[8];
#pragma unroll
  for (int t = 0; t < 8; t++) {
    blv[t] = bl[t * 16 + m];
    bav[t] = ba[t * 16 + m];
  }
#pragma unroll
  for (int r = 0; r < 4; r++) {
    int row = R + q * 4 + r;
    if (row < N_NODES) {
      float dg = (float)(off[row + 1] - off[row]);
#pragma unroll
      for (int t = 0; t < 8; t++)
        out[(size_t)row * D + t * 16 + m] = acc[t][r] + blv[t] + dg * bav[t];
    }
  }
}

// ================= fallback kernels (tiers 0-2) =================

__global__ __launch_bounds__(256) void hist_kernel(const int* __restrict__ ei,
                                                   int* __restrict__ cnt) {
  int e = blockIdx.x * 256 + threadIdx.x;
  if (e < N_EDGES) atomicAdd(&cnt[ei[e]], 1);
}

__global__ __launch_bounds__(256) void block_sum_kernel(const int* __restrict__ cnt,
                                                        int* __restrict__ bsum) {
  int base = blockIdx.x * SCAN_CHUNK;
  int s = 0;
#pragma unroll
  for (int k = 0; k < 4; k++) {
    int i = base + (int)threadIdx.x + k * 256;
    if (i < N_NODES) s += cnt[i];
  }
  __shared__ int red[4];
  for (int o = 32; o > 0; o >>= 1) s += __shfl_down(s, o, 64);
  if ((threadIdx.x & 63) == 0) red[threadIdx.x >> 6] = s;
  __syncthreads();
  if (threadIdx.x == 0) bsum[blockIdx.x] = red[0] + red[1] + red[2] + red[3];
}

__global__ __launch_bounds__(128) void scan_bsum_kernel(int* __restrict__ bsum,
                                                        int* __restrict__ off) {
  __shared__ int sh[128];
  int t = threadIdx.x;
  int v = (t < NB_SCAN) ? bsum[t] : 0;
  sh[t] = v;
  __syncthreads();
  for (int o = 1; o < 128; o <<= 1) {
    int add = (t >= o) ? sh[t - o] : 0;
    __syncthreads();
    sh[t] += add;
    __syncthreads();
  }
  if (t < NB_SCAN) bsum[t] = sh[t] - v;
  if (t == 0) off[N_NODES] = sh[127];
}

__global__ __launch_bounds__(256) void scan_offsets_kernel(const int* __restrict__ cnt,
                                                           const int* __restrict__ bsum,
                                                           int* __restrict__ off) {
  __shared__ int sh[256];
  int t = threadIdx.x;
  int i0 = blockIdx.x * SCAN_CHUNK + t * 4;
  int c[4];
#pragma unroll
  for (int k = 0; k < 4; k++) c[k] = (i0 + k < N_NODES) ? cnt[i0 + k] : 0;
  int ls = c[0] + c[1] + c[2] + c[3];
  sh[t] = ls;
  __syncthreads();
  for (int o = 1; o < 256; o <<= 1) {
    int add = (t >= o) ? sh[t - o] : 0;
    __syncthreads();
    sh[t] += add;
    __syncthreads();
  }
  int run = bsum[blockIdx.x] + sh[t] - ls;
#pragma unroll
  for (int k = 0; k < 4; k++) {
    if (i0 + k < N_NODES) off[i0 + k] = run;
    run += c[k];
  }
}

__global__ __launch_bounds__(256) void fill_kernel(const int* __restrict__ ei,
                                                   const float* __restrict__ ew,
                                                   const int* __restrict__ off,
                                                   int* __restrict__ cur,
                                                   int2* __restrict__ srt) {
  int e = blockIdx.x * 256 + threadIdx.x;
  if (e >= N_EDGES) return;
  int dst = ei[e];
  int p = off[dst] + atomicAdd(&cur[dst], 1);
  srt[p] = make_int2(ei[N_EDGES + e], __float_as_int(ew[e]));
}

__global__ __launch_bounds__(256) void convert_kernel(const float* __restrict__ x,
                                                      uint4* __restrict__ xh) {
  int i = blockIdx.x * 256 + threadIdx.x;
  const float4* xp = reinterpret_cast<const float4*>(x);
  float4 a = xp[(size_t)i * 2];
  float4 b = xp[(size_t)i * 2 + 1];
  uint4 o;
  o.x = bf16rne(a.x) | (bf16rne(a.y) << 16);
  o.y = bf16rne(a.z) | (bf16rne(a.w) << 16);
  o.z = bf16rne(b.x) | (bf16rne(b.y) << 16);
  o.w = bf16rne(b.z) | (bf16rne(b.w) << 16);
  xh[i] = o;
}

__global__ __launch_bounds__(256) void gather_bf16_kernel(const unsigned* __restrict__ xh,
                                                          const int* __restrict__ off,
                                                          const int2* __restrict__ srt,
                                                          float* __restrict__ z,
                                                          float* __restrict__ degf) {
  int gid = blockIdx.x * 256 + threadIdx.x;
  int n = gid >> 5;
  int lane = gid & 31;
  if (n >= N_NODES) return;
  int beg = off[n], end = off[n + 1];
  float4 acc = make_float4(0.f, 0.f, 0.f, 0.f);
  int e = beg;
  for (; e + 1 < end; e += 2) {
    int2 r0 = srt[e];
    int2 r1 = srt[e + 1];
    uint2 p0 = *reinterpret_cast<const uint2*>(xh + (size_t)r0.x * 64 + lane * 2);
    uint2 p1 = *reinterpret_cast<const uint2*>(xh + (size_t)r1.x * 64 + lane * 2);
    float w0 = __int_as_float(r0.y);
    float w1 = __int_as_float(r1.y);
    acc.x = fmaf(w0, __uint_as_float(p0.x << 16), acc.x);
    acc.y = fmaf(w0, __uint_as_float(p0.x & 0xffff0000u), acc.y);
    acc.z = fmaf(w0, __uint_as_float(p0.y << 16), acc.z);
    acc.w = fmaf(w0, __uint_as_float(p0.y & 0xffff0000u), acc.w);
    acc.x = fmaf(w1, __uint_as_float(p1.x << 16), acc.x);
    acc.y = fmaf(w1, __uint_as_float(p1.x & 0xffff0000u), acc.y);
    acc.z = fmaf(w1, __uint_as_float(p1.y << 16), acc.z);
    acc.w = fmaf(w1, __uint_as_float(p1.y & 0xffff0000u), acc.w);
  }
  if (e < end) {
    int2 r0 = srt[e];
    uint2 p0 = *reinterpret_cast<const uint2*>(xh + (size_t)r0.x * 64 + lane * 2);
    float w0 = __int_as_float(r0.y);
    acc.x = fmaf(w0, __uint_as_float(p0.x << 16), acc.x);
    acc.y = fmaf(w0, __uint_as_float(p0.x & 0xffff0000u), acc.y);
    acc.z = fmaf(w0, __uint_as_float(p0.y << 16), acc.z);
    acc.w = fmaf(w0, __uint_as_float(p0.y & 0xffff0000u), acc.w);
  }
  *reinterpret_cast<float4*>(z + (size_t)n * D + (lane << 2)) = acc;
  if (lane == 0) degf[n] = (float)(end - beg);
}

__global__ __launch_bounds__(256) void gather_f32_kernel(const float* __restrict__ x,
                                                         const int* __restrict__ off,
                                                         const int2* __restrict__ srt,
                                                         float* __restrict__ z,
                                                         float* __restrict__ degf) {
  int gid = blockIdx.x * 256 + threadIdx.x;
  int n = gid >> 5;
  int lane = gid & 31;
  if (n >= N_NODES) return;
  int beg = off[n], end = off[n + 1];
  float4 acc = make_float4(0.f, 0.f, 0.f, 0.f);
  for (int e = beg; e < end; e++) {
    int2 r0 = srt[e];
    float4 x0 = *reinterpret_cast<const float4*>(x + (size_t)r0.x * D + (lane << 2));
    float w0 = __int_as_float(r0.y);
    acc.x = fmaf(w0, x0.x, acc.x); acc.y = fmaf(w0, x0.y, acc.y);
    acc.z = fmaf(w0, x0.z, acc.z); acc.w = fmaf(w0, x0.w, acc.w);
  }
  *reinterpret_cast<float4*>(z + (size_t)n * D + (lane << 2)) = acc;
  if (lane == 0) degf[n] = (float)(end - beg);
}

__global__ __launch_bounds__(256) void scatter_kernel(const float* __restrict__ x,
                                                      const int* __restrict__ ei,
                                                      const float* __restrict__ ew,
                                                      float* __restrict__ z,
                                                      float* __restrict__ deg) {
  long long g = (long long)blockIdx.x * 256 + threadIdx.x;
  int e = (int)(g >> 5);
  int lane = (int)(g & 31);
  if (e >= N_EDGES) return;
  int dst = ei[e];
  int src = ei[N_EDGES + e];
  float w = ew[e];
  float4 xv = *reinterpret_cast<const float4*>(x + (size_t)src * D + (lane << 2));
  float* o = z + (size_t)dst * D + (lane << 2);
  atomicAdd(o + 0, w * xv.x);
  atomicAdd(o + 1, w * xv.y);
  atomicAdd(o + 2, w * xv.z);
  atomicAdd(o + 3, w * xv.w);
  if (lane == 0) atomicAdd(deg + dst, 1.0f);
}

__global__ __launch_bounds__(256) void fused_gemm_kernel(const float* __restrict__ x,
                                                         const float* __restrict__ Wl,
                                                         const float* __restrict__ bl,
                                                         const float* __restrict__ Wa,
                                                         const float* __restrict__ ba,
                                                         const float* __restrict__ deg,
                                                         float* __restrict__ out) {
  __shared__ float xs[32 * 16];
  __shared__ float zs[32 * 16];
  __shared__ float wls[16 * 128];
  __shared__ float was[16 * 128];
  const int tid = threadIdx.x;
  const int row0 = blockIdx.x * 32;
  const int c4 = tid & 31;
  const int r0 = tid >> 5;
  float4 acc[4];
#pragma unroll
  for (int i = 0; i < 4; i++) acc[i] = make_float4(0.f, 0.f, 0.f, 0.f);

  for (int k0 = 0; k0 < D; k0 += 16) {
    {
      int t = tid & 127;
      int r = t >> 2;
      int kc = (t & 3) << 2;
      const float* sp = (tid < 128) ? x : out;
      float* dp = (tid < 128) ? xs : zs;
      *reinterpret_cast<float4*>(dp + r * 16 + kc) =
          *reinterpret_cast<const float4*>(sp + (size_t)(row0 + r) * D + k0 + kc);
    }
#pragma unroll
    for (int i = 0; i < 2; i++) {
      int f = tid + i * 256;
      int kk = f >> 5;
      int cc = (f & 31) << 2;
      *reinterpret_cast<float4*>(wls + kk * 128 + cc) =
          *reinterpret_cast<const float4*>(Wl + (size_t)(k0 + kk) * D + cc);
      *reinterpret_cast<float4*>(was + kk * 128 + cc) =
          *reinterpret_cast<const float4*>(Wa + (size_t)(k0 + kk) * D + cc);
    }
    __syncthreads();
#pragma unroll
    for (int kk = 0; kk < 16; kk++) {
      float4 wl = *reinterpret_cast<const float4*>(wls + kk * 128 + (c4 << 2));
      float4 wa = *reinterpret_cast<const float4*>(was + kk * 128 + (c4 << 2));
#pragma unroll
      for (int rr = 0; rr < 4; rr++) {
        int r2 = r0 + rr * 8;
        float xv = xs[r2 * 16 + kk];
        float zv = zs[r2 * 16 + kk];
        acc[rr].x = fmaf(xv, wl.x, fmaf(zv, wa.x, acc[rr].x));
        acc[rr].y = fmaf(xv, wl.y, fmaf(zv, wa.y, acc[rr].y));
        acc[rr].z = fmaf(xv, wl.z, fmaf(zv, wa.z, acc[rr].z));
        acc[rr].w = fmaf(xv, wl.w, fmaf(zv, wa.w, acc[rr].w));
      }
    }
    __syncthreads();
  }

  float4 blv = *reinterpret_cast<const float4*>(bl + (c4 << 2));
  float4 bav = *reinterpret_cast<const float4*>(ba + (c4 << 2));
#pragma unroll
  for (int rr = 0; rr < 4; rr++) {
    int r = row0 + r0 + rr * 8;
    float d = deg[r];
    float4 o;
    o.x = acc[rr].x + blv.x + d * bav.x;
    o.y = acc[rr].y + blv.y + d * bav.y;
    o.z = acc[rr].z + blv.z + d * bav.z;
    o.w = acc[rr].w + blv.w + d * bav.w;
    *reinterpret_cast<float4*>(out + (size_t)r * D + (c4 << 2)) = o;
  }
}

extern "C" void kernel_launch(void* const* d_in, const int* in_sizes, int n_in,
                              void* d_out, int out_size, void* d_ws, size_t ws_size,
                              hipStream_t stream) {
  const float* x  = (const float*)d_in[0];
  const int*   ei = (const int*)d_in[1];
  const float* ew = (const float*)d_in[2];
  const float* Wl = (const float*)d_in[3];
  const float* bl = (const float*)d_in[4];
  const float* Wa = (const float*)d_in[5];
  const float* ba = (const float*)d_in[6];
  float* out = (float*)d_out;

  if (ws_size >= WS_T5_BYTES) {
    int* pcur = (int*)d_ws;
    int* off = pcur + T5_OFF;
    unsigned short* fragW = (unsigned short*)(pcur + T5_FRAGW);
    int2* srt = (int2*)(pcur + T5_SRT);
    unsigned* xh = (unsigned*)(pcur + T5_XH);
    unsigned* zh = (unsigned*)(pcur + T5_ZH);
    int2* stage = (int2*)(pcur + T5_ZH);  // time-aliased with zh

    hipMemsetAsync(pcur, 0, NBUCK * sizeof(int), stream);
    part_kernel<<<PART_BLOCKS + CONV_BLOCKS + W_BLOCKS, 256, 0, stream>>>(
        ei, ew, x, Wl, Wa, pcur, stage, (uint4*)xh, fragW);
    binB2_kernel<<<NBUCK, 256, 0, stream>>>(pcur, stage, off, srt);
    gather_zh_kernel<<<N_NODES * 32 / 256, 256, 0, stream>>>(xh, off, srt, zh);
    mfma_gemm_kernel<<<1563, 256, 0, stream>>>((const short*)xh, (const short*)zh,
                                               (const short*)fragW, off, bl, ba, out);
  } else if (ws_size >= WS_T1_BYTES) {
    int*  cnt  = (int*)d_ws;
    int*  off  = cnt + WS_OFF;
    int*  bsum = cnt + WS_BSUM;
    int2* srt  = (int2*)(cnt + WS_SRT);
    float* degf = (float*)cnt;

    hipMemsetAsync(cnt, 0, (size_t)N_NODES * sizeof(int), stream);
    hist_kernel<<<(N_EDGES + 255) / 256, 256, 0, stream>>>(ei, cnt);
    block_sum_kernel<<<NB_SCAN, 256, 0, stream>>>(cnt, bsum);
    scan_bsum_kernel<<<1, 128, 0, stream>>>(bsum, off);
    scan_offsets_kernel<<<NB_SCAN, 256, 0, stream>>>(cnt, bsum, off);
    hipMemsetAsync(cnt, 0, (size_t)N_NODES * sizeof(int), stream);
    fill_kernel<<<(N_EDGES + 255) / 256, 256, 0, stream>>>(ei, ew, off, cnt, srt);

    if (ws_size >= WS_T2_BYTES) {
      unsigned* xh = (unsigned*)(cnt + WS_XH);
      convert_kernel<<<(N_NODES * D / 8) / 256, 256, 0, stream>>>(x, (uint4*)xh);
      gather_bf16_kernel<<<(N_NODES * 32 + 255) / 256, 256, 0, stream>>>(xh, off, srt, out, degf);
    } else {
      gather_f32_kernel<<<(N_NODES * 32 + 255) / 256, 256, 0, stream>>>(x, off, srt, out, degf);
    }
    fused_gemm_kernel<<<N_NODES / 32, 256, 0, stream>>>(x, Wl, bl, Wa, ba, degf, out);
  } else {
    float* deg = (float*)d_ws;
    hipMemsetAsync(out, 0, (size_t)N_NODES * D * sizeof(float), stream);
    hipMemsetAsync(deg, 0, (size_t)N_NODES * sizeof(float), stream);
    scatter_kernel<<<(N_EDGES * 32) / 256, 256, 0, stream>>>(x, ei, ew, out, deg);
    fused_gemm_kernel<<<N_NODES / 32, 256, 0, stream>>>(x, Wl, bl, Wa, ba, deg, out);
  }
}